// Round 24
// baseline (186.106 us; speedup 1.0000x reference)
//
#include <hip/hip_runtime.h>

typedef unsigned short ushort;
typedef short short8 __attribute__((ext_vector_type(8)));
typedef short short4v __attribute__((ext_vector_type(4)));
typedef float f32x4 __attribute__((ext_vector_type(4)));
typedef __attribute__((address_space(3))) unsigned int lds_u32;
typedef __attribute__((address_space(1))) const unsigned int glb_u32;

#define DEVI static __device__ __forceinline__

DEVI ushort f2b(float f) {
  union { float f; unsigned u; } x; x.f = f;
  unsigned r = x.u + 0x7fffu + ((x.u >> 16) & 1u);
  return (ushort)(r >> 16);
}

DEVI void gload_lds16(const ushort* g, ushort* l) {
  __builtin_amdgcn_global_load_lds((glb_u32*)g, (lds_u32*)l, 16, 0, 0);
}

// ------ fused prep: x cast (blocks 0-4095), w_attn^T (4096-7167), w_proj^T -
__global__ __launch_bounds__(256) void prep_kernel(
    const float* __restrict__ x, const float* __restrict__ wa,
    const float* __restrict__ wp, ushort* __restrict__ xb,
    ushort* __restrict__ watT, ushort* __restrict__ wpT) {
  __shared__ float tile[32][33];
  const int bid = blockIdx.x, tid = threadIdx.x;
  if (bid < 4096) {
    int i = bid * 256 + tid;
    const float4* p = (const float4*)x + 2 * (size_t)i;
    float4 a = p[0], b = p[1];
    ushort tmp[8] = { f2b(a.x), f2b(a.y), f2b(a.z), f2b(a.w),
                      f2b(b.x), f2b(b.y), f2b(b.z), f2b(b.w) };
    *(short8*)(xb + 8 * (size_t)i) = *(short8*)tmp;
    return;
  }
  const float* in; ushort* out; int R, C, bx, by;
  if (bid < 7168) {
    int bb = bid - 4096; in = wa; out = watT; R = 1024; C = 3072;
    bx = (bb % 96) * 32; by = (bb / 96) * 32;
  } else {
    int bb = bid - 7168; in = wp; out = wpT; R = 1024; C = 1024;
    bx = (bb % 32) * 32; by = (bb / 32) * 32;
  }
  const int tx = tid & 31, ty = tid >> 5;
#pragma unroll
  for (int i = 0; i < 32; i += 8)
    tile[ty + i][tx] = in[(size_t)(by + ty + i) * C + bx + tx];
  __syncthreads();
#pragma unroll
  for (int i = 0; i < 32; i += 8)
    out[(size_t)(bx + ty + i) * R + by + tx] = f2b(tile[tx][ty + i]);
}

// ---------------- bf16 GEMM, A[M][K] * BT[N][K]^T -> C[M][N] ----------------
// 128x128 tile, BK=64, 4 waves, 32KB LDS, XOR chunk-swizzle (0 conflicts).
// Per-thread global staging pointers hoisted out of the K-loop and stepped
// by BK (kills per-iter 64-bit addr recompute). Bijective XCD-chunk swizzle
// on the linearized grid (nwg % 8 == 0) for B-panel L2 reuse.
// QKV=true: blocks with n0>=2048 (V third, block-uniform) write straight
// into vt[bh][d][2048] as packed ushort4 -- fuses the V transpose.
template <bool OUT_F32, bool QKV>
__global__ __launch_bounds__(256) void gemm_bt_kernel(
    const ushort* __restrict__ A, const ushort* __restrict__ BT,
    void* __restrict__ C_, ushort* __restrict__ vt, int M, int N, int K) {
  __shared__ ushort lA[128 * 64];
  __shared__ ushort lB[128 * 64];
  const int tid = threadIdx.x, lane = tid & 63, wave = tid >> 6;
  const int wr = wave >> 1, wc = wave & 1;
  const int g = lane >> 4, c = lane & 15;
  const int nx = gridDim.x, nwg = nx * gridDim.y;
  int lin = blockIdx.y * nx + blockIdx.x;
  lin = (lin & 7) * (nwg >> 3) + (lin >> 3);   // bijective: nwg % 8 == 0
  const int m0 = (lin % nx) * 128, n0 = (lin / nx) * 128;

  // hoisted per-thread staging pointers, stepped by BK=64 each iteration
  const ushort* ap0; const ushort* ap1; const ushort* ap2; const ushort* ap3;
  const ushort* bp0; const ushort* bp1; const ushort* bp2; const ushort* bp3;
  {
    int r0 = tid >> 3,        c0 = (tid & 7) ^ (r0 & 7);
    int r1 = (256 + tid) >> 3, c1 = (tid & 7) ^ (r1 & 7);
    int r2 = (512 + tid) >> 3, c2 = (tid & 7) ^ (r2 & 7);
    int r3 = (768 + tid) >> 3, c3 = (tid & 7) ^ (r3 & 7);
    ap0 = A + (size_t)(m0 + r0) * K + c0 * 8;
    ap1 = A + (size_t)(m0 + r1) * K + c1 * 8;
    ap2 = A + (size_t)(m0 + r2) * K + c2 * 8;
    ap3 = A + (size_t)(m0 + r3) * K + c3 * 8;
    bp0 = BT + (size_t)(n0 + r0) * K + c0 * 8;
    bp1 = BT + (size_t)(n0 + r1) * K + c1 * 8;
    bp2 = BT + (size_t)(n0 + r2) * K + c2 * 8;
    bp3 = BT + (size_t)(n0 + r3) * K + c3 * 8;
  }

  f32x4 acc[4][4] = {};
  for (int kt = 0; kt < K; kt += 64) {
    __syncthreads();
    gload_lds16(ap0, lA + (size_t)tid * 8);
    gload_lds16(ap1, lA + (size_t)(256 + tid) * 8);
    gload_lds16(ap2, lA + (size_t)(512 + tid) * 8);
    gload_lds16(ap3, lA + (size_t)(768 + tid) * 8);
    gload_lds16(bp0, lB + (size_t)tid * 8);
    gload_lds16(bp1, lB + (size_t)(256 + tid) * 8);
    gload_lds16(bp2, lB + (size_t)(512 + tid) * 8);
    gload_lds16(bp3, lB + (size_t)(768 + tid) * 8);
    ap0 += 64; ap1 += 64; ap2 += 64; ap3 += 64;
    bp0 += 64; bp1 += 64; bp2 += 64; bp3 += 64;
    __syncthreads();
#pragma unroll
    for (int kk = 0; kk < 2; ++kk) {
      short8 af[4], bf[4];
#pragma unroll
      for (int mi = 0; mi < 4; ++mi) {
        int ra = wr * 64 + mi * 16 + c;
        af[mi] = *(const short8*)&lA[ra * 64 + (((kk * 4 + g) ^ (ra & 7)) * 8)];
      }
#pragma unroll
      for (int ni = 0; ni < 4; ++ni) {
        int rb = wc * 64 + ni * 16 + c;
        bf[ni] = *(const short8*)&lB[rb * 64 + (((kk * 4 + g) ^ (rb & 7)) * 8)];
      }
#pragma unroll
      for (int mi = 0; mi < 4; ++mi)
#pragma unroll
        for (int ni = 0; ni < 4; ++ni)
          acc[mi][ni] = __builtin_amdgcn_mfma_f32_16x16x32_bf16(af[mi], bf[ni], acc[mi][ni], 0, 0, 0);
    }
  }
  if (QKV && n0 >= 2048) {
    // V third: write transposed into vt[bh][d][2048]
#pragma unroll
    for (int mi = 0; mi < 4; ++mi)
#pragma unroll
      for (int ni = 0; ni < 4; ++ni) {
        int mrow0 = m0 + wr * 64 + mi * 16 + g * 4;
        int ncol = n0 - 2048 + wc * 64 + ni * 16 + c;
        int b = mrow0 >> 11, t0 = mrow0 & 2047;
        int hh = ncol >> 6, d = ncol & 63;
        ushort tmp[4] = { f2b(acc[mi][ni][0]), f2b(acc[mi][ni][1]),
                          f2b(acc[mi][ni][2]), f2b(acc[mi][ni][3]) };
        *(short4v*)&vt[((size_t)(b * 16 + hh) * 64 + d) * 2048 + t0] = *(short4v*)tmp;
      }
    return;
  }
#pragma unroll
  for (int mi = 0; mi < 4; ++mi)
#pragma unroll
    for (int ni = 0; ni < 4; ++ni)
#pragma unroll
      for (int r = 0; r < 4; ++r) {
        int mrow = m0 + wr * 64 + mi * 16 + g * 4 + r;
        int ncol = n0 + wc * 64 + ni * 16 + c;
        if (OUT_F32) ((float*)C_)[(size_t)mrow * N + ncol] = acc[mi][ni][r];
        else         ((ushort*)C_)[(size_t)mrow * N + ncol] = f2b(acc[mi][ni][r]);
      }
}

// -------------- attention per-tile compute: fixed-shift softmax ------------
DEVI void attn_compute(const short8 (&qf)[2], f32x4 (&o)[4], float (&l)[4],
                       int qb_t, int kv, const ushort* __restrict__ kb,
                       const ushort* __restrict__ vb, ushort* __restrict__ pW,
                       int wave, int g, int c, int e) {
  const float C1 = 0.18033688011112042f;   // (1/8) * log2(e)
  const float SH = 17.312340490667562f;    // 12 * log2(e)
  f32x4 s[4];
#pragma unroll
  for (int n = 0; n < 4; ++n) {
    short8 kf0 = *(const short8*)&kb[(n * 16 + c) * 64 + ((g ^ e) * 8)];
    short8 kf1 = *(const short8*)&kb[(n * 16 + c) * 64 + (((4 + g) ^ e) * 8)];
    s[n] = (f32x4){0.f, 0.f, 0.f, 0.f};
    s[n] = __builtin_amdgcn_mfma_f32_16x16x32_bf16(qf[0], kf0, s[n], 0, 0, 0);
    s[n] = __builtin_amdgcn_mfma_f32_16x16x32_bf16(qf[1], kf1, s[n], 0, 0, 0);
  }
  if (kv == qb_t) {
#pragma unroll
    for (int n = 0; n < 4; ++n)
#pragma unroll
      for (int r = 0; r < 4; ++r)
        if ((n * 16 + c) > (wave * 16 + g * 4 + r)) s[n][r] = -INFINITY;
  }
#pragma unroll
  for (int n = 0; n < 4; ++n)
#pragma unroll
    for (int r = 0; r < 4; ++r) {
      float p = __builtin_amdgcn_exp2f(fmaf(s[n][r], C1, -SH));
      l[r] += p;
      union { float f; unsigned u; } pu; pu.f = p;
      int row = g * 4 + r;
      pW[row * 64 + (((n * 2 + (c >> 3)) ^ (row & 7)) * 8) + (c & 7)] =
          (ushort)((pu.u + 0x8000u) >> 16);
    }
  short8 pf0 = *(const short8*)&pW[c * 64 + ((g ^ e) * 8)];
  short8 pf1 = *(const short8*)&pW[c * 64 + (((4 + g) ^ e) * 8)];
#pragma unroll
  for (int dg = 0; dg < 4; ++dg) {
    short8 vf0 = *(const short8*)&vb[(dg * 16 + c) * 64 + ((g ^ e) * 8)];
    short8 vf1 = *(const short8*)&vb[(dg * 16 + c) * 64 + (((4 + g) ^ e) * 8)];
    o[dg] = __builtin_amdgcn_mfma_f32_16x16x32_bf16(pf0, vf0, o[dg], 0, 0, 0);
    o[dg] = __builtin_amdgcn_mfma_f32_16x16x32_bf16(pf1, vf1, o[dg], 0, 0, 0);
  }
}

DEVI void attn_store(const f32x4 (&o)[4], float (&l)[4], ushort* __restrict__ y,
                     int b, int h, int qb_t, int wave, int g, int c) {
#pragma unroll
  for (int r = 0; r < 4; ++r) {
    float s0 = l[r];
    s0 += __shfl_xor(s0, 1);
    s0 += __shfl_xor(s0, 2);
    s0 += __shfl_xor(s0, 4);
    s0 += __shfl_xor(s0, 8);
    l[r] = 1.0f / s0;
  }
#pragma unroll
  for (int dg = 0; dg < 4; ++dg)
#pragma unroll
    for (int r = 0; r < 4; ++r) {
      size_t row = (size_t)b * 2048 + qb_t * 64 + wave * 16 + g * 4 + r;
      y[row * 1024 + h * 64 + dg * 16 + c] = f2b(o[dg][r] * l[r]);
    }
}

// ---------------- flash attention, causal, paired q-blocks -----------------
// T14 async-STAGE split (round-20/21 proven, ~77.5us): K/V for tile kv+1
// loaded into REGISTERS right after tile kv publishes; HBM latency hides
// under tile kv's computes; regs committed to LDS after the WAR barrier.
__global__ __launch_bounds__(256, 2) void attn_kernel(
    const ushort* __restrict__ qkv, const ushort* __restrict__ vt,
    ushort* __restrict__ y) {
  __shared__ ushort kT[64 * 64];
  __shared__ ushort vT[64 * 64];
  __shared__ ushort pB[4][16 * 64];
  const int tid = threadIdx.x, lane = tid & 63, wave = tid >> 6;
  const int g = lane >> 4, c = lane & 15, e = c & 7;
  const int j = blockIdx.x, bh = blockIdx.y;
  const int b = bh >> 4, h = bh & 15;
  const int qb0 = j, qb1 = 31 - j;
  const size_t base = (size_t)b * 2048 * 3072 + (size_t)h * 64;
  const ushort* qp = qkv + base;
  const ushort* kp = qkv + base + 1024;
  const ushort* vp = vt + (size_t)bh * 64 * 2048;

  short8 qf0[2], qf1[2];
  {
    int qrow0 = qb0 * 64 + wave * 16 + c;
    int qrow1 = qb1 * 64 + wave * 16 + c;
    qf0[0] = *(const short8*)(qp + (size_t)qrow0 * 3072 + g * 8);
    qf0[1] = *(const short8*)(qp + (size_t)qrow0 * 3072 + 32 + g * 8);
    qf1[0] = *(const short8*)(qp + (size_t)qrow1 * 3072 + g * 8);
    qf1[1] = *(const short8*)(qp + (size_t)qrow1 * 3072 + 32 + g * 8);
  }
  f32x4 o0[4] = {}, o1[4] = {};
  float l0[4] = {0.f, 0.f, 0.f, 0.f}, l1[4] = {0.f, 0.f, 0.f, 0.f};

  short8 kr0, kr1, vr0, vr1;
  const int row0 = tid >> 3, ch0 = tid & 7;
  const int row1 = (256 + tid) >> 3, ch1 = tid & 7;
  const int cs0 = ch0 ^ (row0 & 7), cs1 = ch1 ^ (row1 & 7);

  auto issue = [&](int kv) {
    kr0 = *(const short8*)(kp + (size_t)(kv * 64 + row0) * 3072 + cs0 * 8);
    kr1 = *(const short8*)(kp + (size_t)(kv * 64 + row1) * 3072 + cs1 * 8);
    vr0 = *(const short8*)(vp + (size_t)row0 * 2048 + kv * 64 + cs0 * 8);
    vr1 = *(const short8*)(vp + (size_t)row1 * 2048 + kv * 64 + cs1 * 8);
  };
  auto commit = [&]() {
    *(short8*)&kT[tid * 8] = kr0;
    *(short8*)&kT[(256 + tid) * 8] = kr1;
    *(short8*)&vT[tid * 8] = vr0;
    *(short8*)&vT[(256 + tid) * 8] = vr1;
  };

  issue(0);
  for (int kv = 0; kv <= qb1; ++kv) {
    commit();
    __syncthreads();
    if (kv < qb1) issue(kv + 1);
    attn_compute(qf1, o1, l1, qb1, kv, kT, vT, pB[wave], wave, g, c, e);
    if (kv <= qb0)
      attn_compute(qf0, o0, l0, qb0, kv, kT, vT, pB[wave], wave, g, c, e);
    __syncthreads();
  }

  attn_store(o0, l0, y, b, h, qb0, wave, g, c);
  attn_store(o1, l1, y, b, h, qb1, wave, g, c);
}

extern "C" void kernel_launch(void* const* d_in, const int* in_sizes, int n_in,
                              void* d_out, int out_size, void* d_ws, size_t ws_size,
                              hipStream_t stream) {
  const float* x      = (const float*)d_in[0];
  const float* w_attn = (const float*)d_in[1];
  const float* w_proj = (const float*)d_in[2];
  float* out = (float*)d_out;

  ushort* xb   = (ushort*)d_ws;                   // 8192*1024
  ushort* watT = xb   + (size_t)8192 * 1024;      // 3072*1024
  ushort* wpT  = watT + (size_t)3072 * 1024;      // 1024*1024
  ushort* qkvb = wpT  + (size_t)1024 * 1024;      // 8192*3072 (V third unused)
  ushort* yb   = qkvb + (size_t)8192 * 3072;      // 8192*1024
  ushort* vtb  = yb   + (size_t)8192 * 1024;      // 64*64*2048 (V^T per head)

  prep_kernel<<<8192, 256, 0, stream>>>(x, w_attn, w_proj, xb, watT, wpT);
  gemm_bt_kernel<false, true><<<dim3(64, 24), 256, 0, stream>>>(
      xb, watT, qkvb, vtb, 8192, 3072, 1024);
  attn_kernel<<<dim3(16, 64), 256, 0, stream>>>(qkvb, vtb, yb);
  gemm_bt_kernel<true, false><<<dim3(64, 8), 256, 0, stream>>>(
      yb, wpT, out, nullptr, 8192, 1024, 1024);
}

// Round 25
// 171.222 us; speedup vs baseline: 1.0869x; 1.0869x over previous
//
#include <hip/hip_runtime.h>

typedef unsigned short ushort;
typedef short short8 __attribute__((ext_vector_type(8)));
typedef short short4v __attribute__((ext_vector_type(4)));
typedef float f32x4 __attribute__((ext_vector_type(4)));
typedef __attribute__((address_space(3))) unsigned int lds_u32;
typedef __attribute__((address_space(1))) const unsigned int glb_u32;

#define DEVI static __device__ __forceinline__

DEVI ushort f2b(float f) {
  union { float f; unsigned u; } x; x.f = f;
  unsigned r = x.u + 0x7fffu + ((x.u >> 16) & 1u);
  return (ushort)(r >> 16);
}

DEVI void gload_lds16(const ushort* g, ushort* l) {
  __builtin_amdgcn_global_load_lds((glb_u32*)g, (lds_u32*)l, 16, 0, 0);
}

// ------ fused prep: x cast (blocks 0-4095), w_attn^T (4096-7167), w_proj^T -
__global__ __launch_bounds__(256) void prep_kernel(
    const float* __restrict__ x, const float* __restrict__ wa,
    const float* __restrict__ wp, ushort* __restrict__ xb,
    ushort* __restrict__ watT, ushort* __restrict__ wpT) {
  __shared__ float tile[32][33];
  const int bid = blockIdx.x, tid = threadIdx.x;
  if (bid < 4096) {
    int i = bid * 256 + tid;
    const float4* p = (const float4*)x + 2 * (size_t)i;
    float4 a = p[0], b = p[1];
    ushort tmp[8] = { f2b(a.x), f2b(a.y), f2b(a.z), f2b(a.w),
                      f2b(b.x), f2b(b.y), f2b(b.z), f2b(b.w) };
    *(short8*)(xb + 8 * (size_t)i) = *(short8*)tmp;
    return;
  }
  const float* in; ushort* out; int R, C, bx, by;
  if (bid < 7168) {
    int bb = bid - 4096; in = wa; out = watT; R = 1024; C = 3072;
    bx = (bb % 96) * 32; by = (bb / 96) * 32;
  } else {
    int bb = bid - 7168; in = wp; out = wpT; R = 1024; C = 1024;
    bx = (bb % 32) * 32; by = (bb / 32) * 32;
  }
  const int tx = tid & 31, ty = tid >> 5;
#pragma unroll
  for (int i = 0; i < 32; i += 8)
    tile[ty + i][tx] = in[(size_t)(by + ty + i) * C + bx + tx];
  __syncthreads();
#pragma unroll
  for (int i = 0; i < 32; i += 8)
    out[(size_t)(bx + ty + i) * R + by + tx] = f2b(tile[tx][ty + i]);
}

// ---------------- bf16 GEMM, A[M][K] * BT[N][K]^T -> C[M][N] ----------------
// 128x128 tile, BK=64, 4 waves, 32KB LDS, XOR chunk-swizzle (0 conflicts).
// Per-thread global staging pointers hoisted out of the K-loop and stepped
// by BK (VALUBusy 44->33%, measured r24). NO XCD swizzle: natural x-major
// dispatch keeps all XCDs on the same B-panel streaming A once (the chunk
// swizzle forced each XCD to stream all of A: FETCH 41->180MB, r24).
// QKV=true: blocks with n0>=2048 (V third, block-uniform) write straight
// into vt[bh][d][2048] as packed ushort4 -- fuses the V transpose.
template <bool OUT_F32, bool QKV>
__global__ __launch_bounds__(256) void gemm_bt_kernel(
    const ushort* __restrict__ A, const ushort* __restrict__ BT,
    void* __restrict__ C_, ushort* __restrict__ vt, int M, int N, int K) {
  __shared__ ushort lA[128 * 64];
  __shared__ ushort lB[128 * 64];
  const int tid = threadIdx.x, lane = tid & 63, wave = tid >> 6;
  const int wr = wave >> 1, wc = wave & 1;
  const int g = lane >> 4, c = lane & 15;
  const int m0 = blockIdx.x * 128, n0 = blockIdx.y * 128;

  // hoisted per-thread staging pointers, stepped by BK=64 each iteration
  const ushort* ap0; const ushort* ap1; const ushort* ap2; const ushort* ap3;
  const ushort* bp0; const ushort* bp1; const ushort* bp2; const ushort* bp3;
  {
    int r0 = tid >> 3,        c0 = (tid & 7) ^ (r0 & 7);
    int r1 = (256 + tid) >> 3, c1 = (tid & 7) ^ (r1 & 7);
    int r2 = (512 + tid) >> 3, c2 = (tid & 7) ^ (r2 & 7);
    int r3 = (768 + tid) >> 3, c3 = (tid & 7) ^ (r3 & 7);
    ap0 = A + (size_t)(m0 + r0) * K + c0 * 8;
    ap1 = A + (size_t)(m0 + r1) * K + c1 * 8;
    ap2 = A + (size_t)(m0 + r2) * K + c2 * 8;
    ap3 = A + (size_t)(m0 + r3) * K + c3 * 8;
    bp0 = BT + (size_t)(n0 + r0) * K + c0 * 8;
    bp1 = BT + (size_t)(n0 + r1) * K + c1 * 8;
    bp2 = BT + (size_t)(n0 + r2) * K + c2 * 8;
    bp3 = BT + (size_t)(n0 + r3) * K + c3 * 8;
  }

  f32x4 acc[4][4] = {};
  for (int kt = 0; kt < K; kt += 64) {
    __syncthreads();
    gload_lds16(ap0, lA + (size_t)tid * 8);
    gload_lds16(ap1, lA + (size_t)(256 + tid) * 8);
    gload_lds16(ap2, lA + (size_t)(512 + tid) * 8);
    gload_lds16(ap3, lA + (size_t)(768 + tid) * 8);
    gload_lds16(bp0, lB + (size_t)tid * 8);
    gload_lds16(bp1, lB + (size_t)(256 + tid) * 8);
    gload_lds16(bp2, lB + (size_t)(512 + tid) * 8);
    gload_lds16(bp3, lB + (size_t)(768 + tid) * 8);
    ap0 += 64; ap1 += 64; ap2 += 64; ap3 += 64;
    bp0 += 64; bp1 += 64; bp2 += 64; bp3 += 64;
    __syncthreads();
#pragma unroll
    for (int kk = 0; kk < 2; ++kk) {
      short8 af[4], bf[4];
#pragma unroll
      for (int mi = 0; mi < 4; ++mi) {
        int ra = wr * 64 + mi * 16 + c;
        af[mi] = *(const short8*)&lA[ra * 64 + (((kk * 4 + g) ^ (ra & 7)) * 8)];
      }
#pragma unroll
      for (int ni = 0; ni < 4; ++ni) {
        int rb = wc * 64 + ni * 16 + c;
        bf[ni] = *(const short8*)&lB[rb * 64 + (((kk * 4 + g) ^ (rb & 7)) * 8)];
      }
#pragma unroll
      for (int mi = 0; mi < 4; ++mi)
#pragma unroll
        for (int ni = 0; ni < 4; ++ni)
          acc[mi][ni] = __builtin_amdgcn_mfma_f32_16x16x32_bf16(af[mi], bf[ni], acc[mi][ni], 0, 0, 0);
    }
  }
  if (QKV && n0 >= 2048) {
    // V third: write transposed into vt[bh][d][2048]
#pragma unroll
    for (int mi = 0; mi < 4; ++mi)
#pragma unroll
      for (int ni = 0; ni < 4; ++ni) {
        int mrow0 = m0 + wr * 64 + mi * 16 + g * 4;
        int ncol = n0 - 2048 + wc * 64 + ni * 16 + c;
        int b = mrow0 >> 11, t0 = mrow0 & 2047;
        int hh = ncol >> 6, d = ncol & 63;
        ushort tmp[4] = { f2b(acc[mi][ni][0]), f2b(acc[mi][ni][1]),
                          f2b(acc[mi][ni][2]), f2b(acc[mi][ni][3]) };
        *(short4v*)&vt[((size_t)(b * 16 + hh) * 64 + d) * 2048 + t0] = *(short4v*)tmp;
      }
    return;
  }
#pragma unroll
  for (int mi = 0; mi < 4; ++mi)
#pragma unroll
    for (int ni = 0; ni < 4; ++ni)
#pragma unroll
      for (int r = 0; r < 4; ++r) {
        int mrow = m0 + wr * 64 + mi * 16 + g * 4 + r;
        int ncol = n0 + wc * 64 + ni * 16 + c;
        if (OUT_F32) ((float*)C_)[(size_t)mrow * N + ncol] = acc[mi][ni][r];
        else         ((ushort*)C_)[(size_t)mrow * N + ncol] = f2b(acc[mi][ni][r]);
      }
}

// -------------- attention per-tile compute: fixed-shift softmax ------------
DEVI void attn_compute(const short8 (&qf)[2], f32x4 (&o)[4], float (&l)[4],
                       int qb_t, int kv, const ushort* __restrict__ kb,
                       const ushort* __restrict__ vb, ushort* __restrict__ pW,
                       int wave, int g, int c, int e) {
  const float C1 = 0.18033688011112042f;   // (1/8) * log2(e)
  const float SH = 17.312340490667562f;    // 12 * log2(e)
  f32x4 s[4];
#pragma unroll
  for (int n = 0; n < 4; ++n) {
    short8 kf0 = *(const short8*)&kb[(n * 16 + c) * 64 + ((g ^ e) * 8)];
    short8 kf1 = *(const short8*)&kb[(n * 16 + c) * 64 + (((4 + g) ^ e) * 8)];
    s[n] = (f32x4){0.f, 0.f, 0.f, 0.f};
    s[n] = __builtin_amdgcn_mfma_f32_16x16x32_bf16(qf[0], kf0, s[n], 0, 0, 0);
    s[n] = __builtin_amdgcn_mfma_f32_16x16x32_bf16(qf[1], kf1, s[n], 0, 0, 0);
  }
  if (kv == qb_t) {
#pragma unroll
    for (int n = 0; n < 4; ++n)
#pragma unroll
      for (int r = 0; r < 4; ++r)
        if ((n * 16 + c) > (wave * 16 + g * 4 + r)) s[n][r] = -INFINITY;
  }
#pragma unroll
  for (int n = 0; n < 4; ++n)
#pragma unroll
    for (int r = 0; r < 4; ++r) {
      float p = __builtin_amdgcn_exp2f(fmaf(s[n][r], C1, -SH));
      l[r] += p;
      union { float f; unsigned u; } pu; pu.f = p;
      int row = g * 4 + r;
      pW[row * 64 + (((n * 2 + (c >> 3)) ^ (row & 7)) * 8) + (c & 7)] =
          (ushort)((pu.u + 0x8000u) >> 16);
    }
  short8 pf0 = *(const short8*)&pW[c * 64 + ((g ^ e) * 8)];
  short8 pf1 = *(const short8*)&pW[c * 64 + (((4 + g) ^ e) * 8)];
#pragma unroll
  for (int dg = 0; dg < 4; ++dg) {
    short8 vf0 = *(const short8*)&vb[(dg * 16 + c) * 64 + ((g ^ e) * 8)];
    short8 vf1 = *(const short8*)&vb[(dg * 16 + c) * 64 + (((4 + g) ^ e) * 8)];
    o[dg] = __builtin_amdgcn_mfma_f32_16x16x32_bf16(pf0, vf0, o[dg], 0, 0, 0);
    o[dg] = __builtin_amdgcn_mfma_f32_16x16x32_bf16(pf1, vf1, o[dg], 0, 0, 0);
  }
}

DEVI void attn_store(const f32x4 (&o)[4], float (&l)[4], ushort* __restrict__ y,
                     int b, int h, int qb_t, int wave, int g, int c) {
#pragma unroll
  for (int r = 0; r < 4; ++r) {
    float s0 = l[r];
    s0 += __shfl_xor(s0, 1);
    s0 += __shfl_xor(s0, 2);
    s0 += __shfl_xor(s0, 4);
    s0 += __shfl_xor(s0, 8);
    l[r] = 1.0f / s0;
  }
#pragma unroll
  for (int dg = 0; dg < 4; ++dg)
#pragma unroll
    for (int r = 0; r < 4; ++r) {
      size_t row = (size_t)b * 2048 + qb_t * 64 + wave * 16 + g * 4 + r;
      y[row * 1024 + h * 64 + dg * 16 + c] = f2b(o[dg][r] * l[r]);
    }
}

// ---------------- flash attention, causal, paired q-blocks -----------------
// T14 async-STAGE split (round-20/21 proven, ~77.5us): K/V for tile kv+1
// loaded into REGISTERS right after tile kv publishes; HBM latency hides
// under tile kv's computes; regs committed to LDS after the WAR barrier.
__global__ __launch_bounds__(256, 2) void attn_kernel(
    const ushort* __restrict__ qkv, const ushort* __restrict__ vt,
    ushort* __restrict__ y) {
  __shared__ ushort kT[64 * 64];
  __shared__ ushort vT[64 * 64];
  __shared__ ushort pB[4][16 * 64];
  const int tid = threadIdx.x, lane = tid & 63, wave = tid >> 6;
  const int g = lane >> 4, c = lane & 15, e = c & 7;
  const int j = blockIdx.x, bh = blockIdx.y;
  const int b = bh >> 4, h = bh & 15;
  const int qb0 = j, qb1 = 31 - j;
  const size_t base = (size_t)b * 2048 * 3072 + (size_t)h * 64;
  const ushort* qp = qkv + base;
  const ushort* kp = qkv + base + 1024;
  const ushort* vp = vt + (size_t)bh * 64 * 2048;

  short8 qf0[2], qf1[2];
  {
    int qrow0 = qb0 * 64 + wave * 16 + c;
    int qrow1 = qb1 * 64 + wave * 16 + c;
    qf0[0] = *(const short8*)(qp + (size_t)qrow0 * 3072 + g * 8);
    qf0[1] = *(const short8*)(qp + (size_t)qrow0 * 3072 + 32 + g * 8);
    qf1[0] = *(const short8*)(qp + (size_t)qrow1 * 3072 + g * 8);
    qf1[1] = *(const short8*)(qp + (size_t)qrow1 * 3072 + 32 + g * 8);
  }
  f32x4 o0[4] = {}, o1[4] = {};
  float l0[4] = {0.f, 0.f, 0.f, 0.f}, l1[4] = {0.f, 0.f, 0.f, 0.f};

  short8 kr0, kr1, vr0, vr1;
  const int row0 = tid >> 3, ch0 = tid & 7;
  const int row1 = (256 + tid) >> 3, ch1 = tid & 7;
  const int cs0 = ch0 ^ (row0 & 7), cs1 = ch1 ^ (row1 & 7);

  auto issue = [&](int kv) {
    kr0 = *(const short8*)(kp + (size_t)(kv * 64 + row0) * 3072 + cs0 * 8);
    kr1 = *(const short8*)(kp + (size_t)(kv * 64 + row1) * 3072 + cs1 * 8);
    vr0 = *(const short8*)(vp + (size_t)row0 * 2048 + kv * 64 + cs0 * 8);
    vr1 = *(const short8*)(vp + (size_t)row1 * 2048 + kv * 64 + cs1 * 8);
  };
  auto commit = [&]() {
    *(short8*)&kT[tid * 8] = kr0;
    *(short8*)&kT[(256 + tid) * 8] = kr1;
    *(short8*)&vT[tid * 8] = vr0;
    *(short8*)&vT[(256 + tid) * 8] = vr1;
  };

  issue(0);
  for (int kv = 0; kv <= qb1; ++kv) {
    commit();
    __syncthreads();
    if (kv < qb1) issue(kv + 1);
    attn_compute(qf1, o1, l1, qb1, kv, kT, vT, pB[wave], wave, g, c, e);
    if (kv <= qb0)
      attn_compute(qf0, o0, l0, qb0, kv, kT, vT, pB[wave], wave, g, c, e);
    __syncthreads();
  }

  attn_store(o0, l0, y, b, h, qb0, wave, g, c);
  attn_store(o1, l1, y, b, h, qb1, wave, g, c);
}

extern "C" void kernel_launch(void* const* d_in, const int* in_sizes, int n_in,
                              void* d_out, int out_size, void* d_ws, size_t ws_size,
                              hipStream_t stream) {
  const float* x      = (const float*)d_in[0];
  const float* w_attn = (const float*)d_in[1];
  const float* w_proj = (const float*)d_in[2];
  float* out = (float*)d_out;

  ushort* xb   = (ushort*)d_ws;                   // 8192*1024
  ushort* watT = xb   + (size_t)8192 * 1024;      // 3072*1024
  ushort* wpT  = watT + (size_t)3072 * 1024;      // 1024*1024
  ushort* qkvb = wpT  + (size_t)1024 * 1024;      // 8192*3072 (V third unused)
  ushort* yb   = qkvb + (size_t)8192 * 3072;      // 8192*1024
  ushort* vtb  = yb   + (size_t)8192 * 1024;      // 64*64*2048 (V^T per head)

  prep_kernel<<<8192, 256, 0, stream>>>(x, w_attn, w_proj, xb, watT, wpT);
  gemm_bt_kernel<false, true><<<dim3(64, 24), 256, 0, stream>>>(
      xb, watT, qkvb, vtb, 8192, 3072, 1024);
  attn_kernel<<<dim3(16, 64), 256, 0, stream>>>(qkvb, vtb, yb);
  gemm_bt_kernel<true, false><<<dim3(64, 8), 256, 0, stream>>>(
      yb, wpT, out, nullptr, 8192, 1024, 1024);
}